// Round 4
// baseline (216.154 us; speedup 1.0000x reference)
//
#include <hip/hip_runtime.h>
#include <math.h>

// Problem constants (from reference setup_inputs)
#define BBATCH 16
#define NPTS   4096
#define MPTS   1024
#define C1c    128
#define C2c    256
#define CINc   384
#define H1c    256
#define H2c    128
#define TN     64

typedef _Float16 f16x8 __attribute__((ext_vector_type(8)));
typedef _Float16 f16x4 __attribute__((ext_vector_type(4)));
typedef float    f32x4 __attribute__((ext_vector_type(4)));

#define LDI  40    // f16 stride, s_inv rows [64 n][32 m] (80 B rows)
#define LDXc 408   // f16 stride, s_X rows [64 n][384 k]
#define LDH  264   // f16 stride, s_H rows [64 n][256 k]

// shared memory union (bytes)
#define OFF_XYZ2  0                    // 12288 B [1024][3] f32      (phase A)
#define OFF_INV   12288                // 2 x 64*LDI*2 = 10240 B     (phase A dbuf)
#define OFF_RED   22528                // 1024 B s_red               (A->B transition)
#define OFF_RECIP 52224                // 256 B s_recip (outside s_X!)
#define SMEM_BYTES 53248               // >= s_X 52224; 3 blocks/CU (159744 <= 163840)

// ws layout (f16 elements)
#define WS_P2H  0
#define WS_W1H  (BBATCH * C2c * MPTS)            // 4194304
#define WS_W2H  (WS_W1H + H1c * CINc)            // +98304
#define WS_F16_TOTAL (WS_W2H + H2c * H1c)        // 4325376 elems = 8650752 B

// ---------------------------------------------------------------------------
// pre-pass: convert p2 / W1 / W2 to f16 into workspace
__global__ __launch_bounds__(256) void cvt_f16(
    const float* __restrict__ p2, const float* __restrict__ W1,
    const float* __restrict__ W2, _Float16* __restrict__ ws)
{
    const int NP2 = BBATCH * C2c * MPTS / 4;   // 1048576 float4s
    const int NW1 = H1c * CINc / 4;            // 24576
    const int i = blockIdx.x * 256 + threadIdx.x;
    float4 v; _Float16* dst;
    if (i < NP2)            { v = ((const float4*)p2)[i];            dst = ws + WS_P2H + (size_t)i * 4; }
    else if (i < NP2 + NW1) { int j = i - NP2; v = ((const float4*)W1)[j]; dst = ws + WS_W1H + (size_t)j * 4; }
    else                    { int j = i - NP2 - NW1; v = ((const float4*)W2)[j]; dst = ws + WS_W2H + (size_t)j * 4; }
    f16x4 h;
    h[0] = (_Float16)v.x; h[1] = (_Float16)v.y; h[2] = (_Float16)v.z; h[3] = (_Float16)v.w;
    *(f16x4*)dst = h;
}

// ---------------------------------------------------------------------------
// Phase A: D = U[c][n], A = p2 chunk in REGISTERS (direct from L2, dbuf),
//          B = inv chunk in LDS (dbuf, generated one step ahead), 1 barrier/step.
//          S[n] via scalar partials + cross-wave reduce.
// Phase B: h = relu(W1 @ concat(p1, U/S) + b1): A = W1h global, B = s_X.
// Phase C: out = relu(W2 @ h + b2):             A = W2h global, B = s_H.
template <bool F16P>
__global__ __launch_bounds__(256, 3) void fp_mfma3(
    const float* __restrict__ xyz1, const float* __restrict__ xyz2,
    const float* __restrict__ p1,   const float* __restrict__ p2,
    const float* __restrict__ W1,   const float* __restrict__ b1v,
    const float* __restrict__ W2,   const float* __restrict__ b2v,
    const _Float16* __restrict__ p2h, const _Float16* __restrict__ W1h,
    const _Float16* __restrict__ W2h,
    float* __restrict__ out)
{
    __shared__ __align__(16) char smem[SMEM_BYTES];
    float*    s_xyz2  = (float*)(smem + OFF_XYZ2);
    _Float16* s_inv   = (_Float16*)(smem + OFF_INV);
    float*    s_red   = (float*)(smem + OFF_RED);
    float*    s_recip = (float*)(smem + OFF_RECIP);
    _Float16* s_X     = (_Float16*)smem;
    _Float16* s_H     = (_Float16*)smem;

    const int tid  = threadIdx.x;
    const int w    = tid >> 6;    // wave 0..3: owns c-rows [w*64, w*64+64) in phase A
    const int L    = tid & 63;
    const int quad = L >> 4;
    const int l16  = L & 15;

    // XCD swizzle: each XCD sees 2 batches -> p2h working set (1 MB) L2-resident
    const int id = blockIdx.x;
    const int b  = (id & 7) * 2 + ((id >> 3) & 1);
    const int n0 = (id >> 4) * TN;

    const float*    __restrict__ p2b  = p2  + (size_t)b * C2c * MPTS;
    const _Float16* __restrict__ p2hb = F16P ? (p2h + (size_t)b * C2c * MPTS) : (const _Float16*)nullptr;
    const float*    __restrict__ z2b  = xyz2 + (size_t)b * MPTS * 3;

    // stage xyz2 (12 KB, float4)
    for (int i = tid; i < MPTS * 3 / 4; i += 256)
        ((f32x4*)s_xyz2)[i] = ((const f32x4*)z2b)[i];

    // inv-gen: this thread owns query n = L, m-slice [s*32 + w*8, +8)
    const float x1x = xyz1[((size_t)b * NPTS + n0 + L) * 3 + 0];
    const float x1y = xyz1[((size_t)b * NPTS + n0 + L) * 3 + 1];
    const float x1z = xyz1[((size_t)b * NPTS + n0 + L) * 3 + 2];

    f32x4 acc[4][4];   // [ct][nt]: rows c = w*64+ct*16+quad*4+r, col n = nt*16+l16
    #pragma unroll
    for (int ct = 0; ct < 4; ++ct)
        #pragma unroll
        for (int nt = 0; nt < 4; ++nt)
            acc[ct][nt] = (f32x4){0.f, 0.f, 0.f, 0.f};

    float ssum = 0.f;

    // A-frag base: c = w*64 + ct*16 + l16, k = quad*8
    const _Float16* aphb = F16P ? (p2hb + (size_t)(w * 64 + l16) * MPTS + quad * 8) : (const _Float16*)nullptr;
    const float*    apfb = p2b + (size_t)(w * 64 + l16) * MPTS + quad * 8;

    f16x8 Aa[2][4];

    __syncthreads();   // xyz2 staged

    // preamble: A chunk 0 + inv chunk 0
    if (F16P) {
        #pragma unroll
        for (int ct = 0; ct < 4; ++ct) Aa[0][ct] = *(const f16x8*)(aphb + ct * (16 * MPTS));
    } else {
        #pragma unroll
        for (int ct = 0; ct < 4; ++ct) {
            const float4 a0 = *(const float4*)(apfb + ct * (16 * MPTS));
            const float4 a1 = *(const float4*)(apfb + ct * (16 * MPTS) + 4);
            f16x8 h;
            h[0] = (_Float16)a0.x; h[1] = (_Float16)a0.y; h[2] = (_Float16)a0.z; h[3] = (_Float16)a0.w;
            h[4] = (_Float16)a1.x; h[5] = (_Float16)a1.y; h[6] = (_Float16)a1.z; h[7] = (_Float16)a1.w;
            Aa[0][ct] = h;
        }
    }
    {
        const float* zp = s_xyz2 + (w * 8) * 3;
        f32x4 zr[6];
        #pragma unroll
        for (int j = 0; j < 6; ++j) zr[j] = ((const f32x4*)zp)[j];
        const float* zv = (const float*)zr;
        f16x8 iv;
        #pragma unroll
        for (int i = 0; i < 8; ++i) {
            const float dx = x1x - zv[3 * i + 0];
            const float dy = x1y - zv[3 * i + 1];
            const float dz = x1z - zv[3 * i + 2];
            const float d2 = fmaf(dx, dx, fmaf(dy, dy, fmaf(dz, dz, 1e-12f)));
            const float inv = __builtin_amdgcn_rsqf(d2);
            ssum += inv;
            iv[i] = (_Float16)inv;
        }
        *(f16x8*)(s_inv + L * LDI + w * 8) = iv;
    }
    __syncthreads();   // inv chunk 0 visible

    #pragma unroll 2
    for (int s = 0; s < 32; ++s) {
        const int cur = s & 1;
        // prefetch A chunk s+1 (L2-latency hidden under gen + MFMA)
        if (s + 1 < 32) {
            if (F16P) {
                const _Float16* ap = aphb + (s + 1) * 32;
                #pragma unroll
                for (int ct = 0; ct < 4; ++ct) Aa[cur ^ 1][ct] = *(const f16x8*)(ap + ct * (16 * MPTS));
            } else {
                const float* ap = apfb + (s + 1) * 32;
                #pragma unroll
                for (int ct = 0; ct < 4; ++ct) {
                    const float4 a0 = *(const float4*)(ap + ct * (16 * MPTS));
                    const float4 a1 = *(const float4*)(ap + ct * (16 * MPTS) + 4);
                    f16x8 h;
                    h[0] = (_Float16)a0.x; h[1] = (_Float16)a0.y; h[2] = (_Float16)a0.z; h[3] = (_Float16)a0.w;
                    h[4] = (_Float16)a1.x; h[5] = (_Float16)a1.y; h[6] = (_Float16)a1.z; h[7] = (_Float16)a1.w;
                    Aa[cur ^ 1][ct] = h;
                }
            }
        }
        // generate inv chunk s+1 into the other buffer (reads of s-1 completed at last barrier)
        if (s + 1 < 32) {
            const float* zp = s_xyz2 + ((s + 1) * 32 + w * 8) * 3;
            f32x4 zr[6];
            #pragma unroll
            for (int j = 0; j < 6; ++j) zr[j] = ((const f32x4*)zp)[j];
            const float* zv = (const float*)zr;
            f16x8 iv;
            #pragma unroll
            for (int i = 0; i < 8; ++i) {
                const float dx = x1x - zv[3 * i + 0];
                const float dy = x1y - zv[3 * i + 1];
                const float dz = x1z - zv[3 * i + 2];
                const float d2 = fmaf(dx, dx, fmaf(dy, dy, fmaf(dz, dz, 1e-12f)));
                const float inv = __builtin_amdgcn_rsqf(d2);
                ssum += inv;
                iv[i] = (_Float16)inv;
            }
            *(f16x8*)(s_inv + (cur ^ 1) * (64 * LDI) + L * LDI + w * 8) = iv;
        }
        // MFMA on chunk s
        const _Float16* bb = s_inv + cur * (64 * LDI) + l16 * LDI + quad * 8;
        #pragma unroll
        for (int nt = 0; nt < 4; ++nt) {
            const f16x8 bf = *(const f16x8*)(bb + nt * (16 * LDI));
            #pragma unroll
            for (int ct = 0; ct < 4; ++ct)
                acc[ct][nt] = __builtin_amdgcn_mfma_f32_16x16x32_f16(Aa[cur][ct], bf, acc[ct][nt], 0, 0, 0);
        }
        __syncthreads();   // reads of s done, writes of s+1 done
    }

    // ---- S[n] reduction: s_red lives in phase-A scratch (consumed before s_X writes) ----
    s_red[tid] = ssum;
    __syncthreads();
    if (tid < 64)
        s_recip[tid] = 1.0f / (s_red[tid] + s_red[tid + 64] + s_red[tid + 128] + s_red[tid + 192]);
    __syncthreads();   // s_recip ready; s_red / s_inv / s_xyz2 now dead

    // interp -> s_X[n][128 + c]  (f16x4: 4 consecutive c per D-reg quad)
    {
        float rn4[4];
        #pragma unroll
        for (int nt = 0; nt < 4; ++nt) rn4[nt] = s_recip[nt * 16 + l16];
        #pragma unroll
        for (int ct = 0; ct < 4; ++ct)
            #pragma unroll
            for (int nt = 0; nt < 4; ++nt) {
                const f32x4 v = acc[ct][nt];
                const float r = rn4[nt];
                f16x4 hv;
                hv[0] = (_Float16)(v[0] * r);
                hv[1] = (_Float16)(v[1] * r);
                hv[2] = (_Float16)(v[2] * r);
                hv[3] = (_Float16)(v[3] * r);
                *(f16x4*)(&s_X[(nt * 16 + l16) * LDXc + 128 + w * 64 + ct * 16 + quad * 4]) = hv;
            }
    }
    // p1 -> s_X[n][c], c in [0,128)
    {
        const float* p1b = p1 + (size_t)b * C1c * NPTS + n0;
        #pragma unroll
        for (int cc = 0; cc < 8; ++cc) {
            const int c = w * 32 + cc * 4;
            f16x4 v;
            v[0] = (_Float16)p1b[(size_t)(c + 0) * NPTS + L];
            v[1] = (_Float16)p1b[(size_t)(c + 1) * NPTS + L];
            v[2] = (_Float16)p1b[(size_t)(c + 2) * NPTS + L];
            v[3] = (_Float16)p1b[(size_t)(c + 3) * NPTS + L];
            *(f16x4*)(&s_X[L * LDXc + c]) = v;
        }
    }
    __syncthreads();   // x matrix complete

    // ---------------- Phase B: h = relu(W1 @ x + b1), K=384 ----------------
    f32x4 hacc[4][4];
    #pragma unroll
    for (int ct = 0; ct < 4; ++ct)
        #pragma unroll
        for (int nt = 0; nt < 4; ++nt)
            hacc[ct][nt] = (f32x4){0.f, 0.f, 0.f, 0.f};

    #pragma unroll 2
    for (int kc = 0; kc < 12; ++kc) {
        f16x8 af[4];
        if (F16P) {
            const _Float16* wp = W1h + (size_t)(w * 64 + l16) * CINc + kc * 32 + quad * 8;
            #pragma unroll
            for (int ct = 0; ct < 4; ++ct) af[ct] = *(const f16x8*)(wp + ct * (16 * CINc));
        } else {
            const float* wp = W1 + (size_t)(w * 64 + l16) * CINc + kc * 32 + quad * 8;
            #pragma unroll
            for (int ct = 0; ct < 4; ++ct) {
                const float4 a0 = *(const float4*)(wp + ct * (16 * CINc));
                const float4 a1 = *(const float4*)(wp + ct * (16 * CINc) + 4);
                f16x8 h;
                h[0] = (_Float16)a0.x; h[1] = (_Float16)a0.y; h[2] = (_Float16)a0.z; h[3] = (_Float16)a0.w;
                h[4] = (_Float16)a1.x; h[5] = (_Float16)a1.y; h[6] = (_Float16)a1.z; h[7] = (_Float16)a1.w;
                af[ct] = h;
            }
        }
        #pragma unroll
        for (int nt = 0; nt < 4; ++nt) {
            const f16x8 bf = *(const f16x8*)(&s_X[(nt * 16 + l16) * LDXc + kc * 32 + quad * 8]);
            #pragma unroll
            for (int ct = 0; ct < 4; ++ct)
                hacc[ct][nt] = __builtin_amdgcn_mfma_f32_16x16x32_f16(af[ct], bf, hacc[ct][nt], 0, 0, 0);
        }
    }

    __syncthreads();   // all s_X reads done before overlaying s_H

    // bias + relu + stage h -> s_H[n][o1]
    {
        f32x4 bb[4];
        #pragma unroll
        for (int ct = 0; ct < 4; ++ct)
            bb[ct] = *(const f32x4*)(b1v + w * 64 + ct * 16 + quad * 4);
        #pragma unroll
        for (int ct = 0; ct < 4; ++ct)
            #pragma unroll
            for (int nt = 0; nt < 4; ++nt) {
                const f32x4 v = hacc[ct][nt];
                f16x4 hv;
                hv[0] = (_Float16)fmaxf(v[0] + bb[ct][0], 0.f);
                hv[1] = (_Float16)fmaxf(v[1] + bb[ct][1], 0.f);
                hv[2] = (_Float16)fmaxf(v[2] + bb[ct][2], 0.f);
                hv[3] = (_Float16)fmaxf(v[3] + bb[ct][3], 0.f);
                *(f16x4*)(&s_H[(nt * 16 + l16) * LDH + w * 64 + ct * 16 + quad * 4]) = hv;
            }
    }
    __syncthreads();

    // ---------------- Phase C: out = relu(W2 @ h + b2), K=256 ----------------
    f32x4 oacc[2][4];
    #pragma unroll
    for (int ct = 0; ct < 2; ++ct)
        #pragma unroll
        for (int nt = 0; nt < 4; ++nt)
            oacc[ct][nt] = (f32x4){0.f, 0.f, 0.f, 0.f};

    #pragma unroll 2
    for (int oc = 0; oc < 8; ++oc) {
        f16x8 af2[2];
        if (F16P) {
            const _Float16* wp = W2h + (size_t)(w * 32 + l16) * H1c + oc * 32 + quad * 8;
            #pragma unroll
            for (int ct = 0; ct < 2; ++ct) af2[ct] = *(const f16x8*)(wp + ct * (16 * H1c));
        } else {
            const float* wp = W2 + (size_t)(w * 32 + l16) * H1c + oc * 32 + quad * 8;
            #pragma unroll
            for (int ct = 0; ct < 2; ++ct) {
                const float4 a0 = *(const float4*)(wp + ct * (16 * H1c));
                const float4 a1 = *(const float4*)(wp + ct * (16 * H1c) + 4);
                f16x8 h;
                h[0] = (_Float16)a0.x; h[1] = (_Float16)a0.y; h[2] = (_Float16)a0.z; h[3] = (_Float16)a0.w;
                h[4] = (_Float16)a1.x; h[5] = (_Float16)a1.y; h[6] = (_Float16)a1.z; h[7] = (_Float16)a1.w;
                af2[ct] = h;
            }
        }
        #pragma unroll
        for (int nt = 0; nt < 4; ++nt) {
            const f16x8 bf = *(const f16x8*)(&s_H[(nt * 16 + l16) * LDH + oc * 32 + quad * 8]);
            #pragma unroll
            for (int ct = 0; ct < 2; ++ct)
                oacc[ct][nt] = __builtin_amdgcn_mfma_f32_16x16x32_f16(af2[ct], bf, oacc[ct][nt], 0, 0, 0);
        }
    }

    // epilogue: bias + relu + store
    {
        f32x4 bb2[2];
        #pragma unroll
        for (int ct = 0; ct < 2; ++ct)
            bb2[ct] = *(const f32x4*)(b2v + w * 32 + ct * 16 + quad * 4);
        #pragma unroll
        for (int ct = 0; ct < 2; ++ct)
            #pragma unroll
            for (int nt = 0; nt < 4; ++nt) {
                float* op = out + ((size_t)b * H2c + w * 32 + ct * 16 + quad * 4) * NPTS
                                + n0 + nt * 16 + l16;
                #pragma unroll
                for (int j = 0; j < 4; ++j)
                    op[(size_t)j * NPTS] = fmaxf(oacc[ct][nt][j] + bb2[ct][j], 0.f);
            }
    }
}

extern "C" void kernel_launch(void* const* d_in, const int* in_sizes, int n_in,
                              void* d_out, int out_size, void* d_ws, size_t ws_size,
                              hipStream_t stream) {
    (void)in_sizes; (void)n_in; (void)out_size;
    const float* xyz1 = (const float*)d_in[0];
    const float* xyz2 = (const float*)d_in[1];
    const float* p1   = (const float*)d_in[2];
    const float* p2   = (const float*)d_in[3];
    const float* W1   = (const float*)d_in[4];
    const float* b1   = (const float*)d_in[5];
    const float* W2   = (const float*)d_in[6];
    const float* b2   = (const float*)d_in[7];
    float* out = (float*)d_out;

    const bool useh = (ws_size >= (size_t)WS_F16_TOTAL * 2);
    dim3 grid(BBATCH * (NPTS / TN));   // 1024 blocks
    dim3 block(256);
    if (useh) {
        _Float16* ws = (_Float16*)d_ws;
        const int ncvt = (BBATCH * C2c * MPTS + H1c * CINc + H2c * H1c) / 4;  // 1081344
        cvt_f16<<<dim3(ncvt / 256), dim3(256), 0, stream>>>(p2, W1, W2, ws);
        fp_mfma3<true><<<grid, block, 0, stream>>>(xyz1, xyz2, p1, p2, W1, b1, W2, b2,
                                                   ws + WS_P2H, ws + WS_W1H, ws + WS_W2H, out);
    } else {
        fp_mfma3<false><<<grid, block, 0, stream>>>(xyz1, xyz2, p1, p2, W1, b1, W2, b2,
                                                    nullptr, nullptr, nullptr, out);
    }
}

// Round 5
// 215.097 us; speedup vs baseline: 1.0049x; 1.0049x over previous
//
#include <hip/hip_runtime.h>
#include <math.h>

// Problem constants (from reference setup_inputs)
#define BBATCH 16
#define NPTS   4096
#define MPTS   1024
#define C1c    128
#define C2c    256
#define CINc   384
#define H1c    256
#define H2c    128
#define TN     64

typedef _Float16 f16x8 __attribute__((ext_vector_type(8)));
typedef _Float16 f16x4 __attribute__((ext_vector_type(4)));
typedef float    f32x4 __attribute__((ext_vector_type(4)));

#define LDI  40    // f16 stride, s_inv rows [64 n][32 m] (80 B rows)
#define LDXc 408   // f16 stride, s_X rows [64 n][384 k]
#define LDH  264   // f16 stride, s_H rows [64 n][256 k]

// shared memory union (bytes)
#define OFF_XYZ2  0                    // 12288 B [1024][3] f32      (phase A)
#define OFF_INV   12288                // 4 x 64*LDI*2 = 20480 B     (phase A, 4-buf)
#define OFF_RED   32768                // 2048 B s_red[512]          (A->B transition)
#define OFF_RECIP 52224                // 256 B s_recip (beyond s_X)
#define SMEM_BYTES 53248               // >= s_X 52224; 3 blocks/CU (159744 <= 163840)

// ws layout (f16 elements)
#define WS_P2H  0
#define WS_W1H  (BBATCH * C2c * MPTS)            // 4194304
#define WS_W2H  (WS_W1H + H1c * CINc)            // +98304
#define WS_F16_TOTAL (WS_W2H + H2c * H1c)        // 4325376 elems = 8650752 B

// ---------------------------------------------------------------------------
// pre-pass: convert p2 / W1 / W2 to f16 into workspace
__global__ __launch_bounds__(256) void cvt_f16(
    const float* __restrict__ p2, const float* __restrict__ W1,
    const float* __restrict__ W2, _Float16* __restrict__ ws)
{
    const int NP2 = BBATCH * C2c * MPTS / 4;   // 1048576 float4s
    const int NW1 = H1c * CINc / 4;            // 24576
    const int i = blockIdx.x * 256 + threadIdx.x;
    float4 v; _Float16* dst;
    if (i < NP2)            { v = ((const float4*)p2)[i];            dst = ws + WS_P2H + (size_t)i * 4; }
    else if (i < NP2 + NW1) { int j = i - NP2; v = ((const float4*)W1)[j]; dst = ws + WS_W1H + (size_t)j * 4; }
    else                    { int j = i - NP2 - NW1; v = ((const float4*)W2)[j]; dst = ws + WS_W2H + (size_t)j * 4; }
    f16x4 h;
    h[0] = (_Float16)v.x; h[1] = (_Float16)v.y; h[2] = (_Float16)v.z; h[3] = (_Float16)v.w;
    *(f16x4*)dst = h;
}

// ---------------------------------------------------------------------------
// 512-thread / 8-wave version. Same dataflow as R4 (A = p2 in registers from
// L2, B = inv in LDS), but: 2x waves per LDS footprint (24 waves/CU), 4-buffer
// inv with ONE barrier per 2 m-chunks (16 barriers), A-prefetch a full
// super-step ahead.
template <bool F16P>
__global__ __launch_bounds__(512, 6) void fp_mfma4(
    const float* __restrict__ xyz1, const float* __restrict__ xyz2,
    const float* __restrict__ p1,   const float* __restrict__ p2,
    const float* __restrict__ W1,   const float* __restrict__ b1v,
    const float* __restrict__ W2,   const float* __restrict__ b2v,
    const _Float16* __restrict__ p2h, const _Float16* __restrict__ W1h,
    const _Float16* __restrict__ W2h,
    float* __restrict__ out)
{
    __shared__ __align__(16) char smem[SMEM_BYTES];
    float*    s_xyz2  = (float*)(smem + OFF_XYZ2);
    _Float16* s_inv   = (_Float16*)(smem + OFF_INV);
    float*    s_red   = (float*)(smem + OFF_RED);
    float*    s_recip = (float*)(smem + OFF_RECIP);
    _Float16* s_X     = (_Float16*)smem;
    _Float16* s_H     = (_Float16*)smem;

    const int tid  = threadIdx.x;   // 0..511
    const int w    = tid >> 6;      // wave 0..7
    const int L    = tid & 63;
    const int quad = L >> 4;
    const int l16  = L & 15;
    const int gm   = w * 4;         // inv-gen: m offset within chunk (4 pts/thread)

    // XCD swizzle: each XCD sees 2 batches -> p2h working set (1 MB f16) L2-resident
    const int id = blockIdx.x;
    const int b  = (id & 7) * 2 + ((id >> 3) & 1);
    const int n0 = (id >> 4) * TN;

    const float*    __restrict__ p2b  = p2  + (size_t)b * C2c * MPTS;
    const _Float16* __restrict__ p2hb = F16P ? (p2h + (size_t)b * C2c * MPTS) : (const _Float16*)nullptr;
    const float*    __restrict__ z2b  = xyz2 + (size_t)b * MPTS * 3;

    // stage xyz2 (12 KB, f32x4: 768 vectors over 512 threads)
    for (int i = tid; i < MPTS * 3 / 4; i += 512)
        ((f32x4*)s_xyz2)[i] = ((const f32x4*)z2b)[i];

    // inv-gen: this thread owns query n = L, m-slice [chunk*32 + gm, +4)
    const float x1x = xyz1[((size_t)b * NPTS + n0 + L) * 3 + 0];
    const float x1y = xyz1[((size_t)b * NPTS + n0 + L) * 3 + 1];
    const float x1z = xyz1[((size_t)b * NPTS + n0 + L) * 3 + 2];

    f32x4 acc[2][4];   // [ct][nt]: row c = w*32+ct*16+quad*4+r, col n = nt*16+l16
    #pragma unroll
    for (int ct = 0; ct < 2; ++ct)
        #pragma unroll
        for (int nt = 0; nt < 4; ++nt)
            acc[ct][nt] = (f32x4){0.f, 0.f, 0.f, 0.f};

    float ssum = 0.f;

    // A-frag base: c = w*32 + ct*16 + l16, k = quad*8
    const _Float16* aphb = F16P ? (p2hb + (size_t)(w * 32 + l16) * MPTS + quad * 8) : (const _Float16*)nullptr;
    const float*    apfb = p2b + (size_t)(w * 32 + l16) * MPTS + quad * 8;

    f16x8 Aa[2][2][2];   // [super-step parity][chunk-in-pair][ct]

    auto loadA = [&](int chunk, f16x8 dst[2]) {
        if (F16P) {
            const _Float16* ap = aphb + chunk * 32;
            #pragma unroll
            for (int ct = 0; ct < 2; ++ct) dst[ct] = *(const f16x8*)(ap + ct * (16 * MPTS));
        } else {
            const float* ap = apfb + chunk * 32;
            #pragma unroll
            for (int ct = 0; ct < 2; ++ct) {
                const float4 a0 = *(const float4*)(ap + ct * (16 * MPTS));
                const float4 a1 = *(const float4*)(ap + ct * (16 * MPTS) + 4);
                f16x8 h;
                h[0] = (_Float16)a0.x; h[1] = (_Float16)a0.y; h[2] = (_Float16)a0.z; h[3] = (_Float16)a0.w;
                h[4] = (_Float16)a1.x; h[5] = (_Float16)a1.y; h[6] = (_Float16)a1.z; h[7] = (_Float16)a1.w;
                dst[ct] = h;
            }
        }
    };

    auto gen = [&](int chunk) {
        const float* zp = s_xyz2 + (chunk * 32 + gm) * 3;   // 48 B aligned
        f32x4 zr[3];
        #pragma unroll
        for (int j = 0; j < 3; ++j) zr[j] = ((const f32x4*)zp)[j];
        const float* zv = (const float*)zr;
        f16x4 iv;
        #pragma unroll
        for (int i = 0; i < 4; ++i) {
            const float dx = x1x - zv[3 * i + 0];
            const float dy = x1y - zv[3 * i + 1];
            const float dz = x1z - zv[3 * i + 2];
            const float d2 = fmaf(dx, dx, fmaf(dy, dy, fmaf(dz, dz, 1e-12f)));
            const float inv = __builtin_amdgcn_rsqf(d2);
            ssum += inv;
            iv[i] = (_Float16)inv;
        }
        *(f16x4*)(s_inv + (chunk & 3) * (64 * LDI) + L * LDI + gm) = iv;
    };

    __syncthreads();   // xyz2 staged

    // preamble: inv chunks 0,1 + A chunks 0,1
    loadA(0, Aa[0][0]);
    loadA(1, Aa[0][1]);
    gen(0);
    gen(1);
    __syncthreads();   // inv chunks 0,1 visible

    #pragma unroll 2
    for (int ss = 0; ss < 16; ++ss) {
        const int pa = ss & 1;
        if (ss < 15) {
            // prefetch A + generate inv for chunks 2ss+2, 2ss+3 (consumed next super-step)
            loadA(2 * ss + 2, Aa[pa ^ 1][0]);
            loadA(2 * ss + 3, Aa[pa ^ 1][1]);
            gen(2 * ss + 2);
            gen(2 * ss + 3);
        }
        // MFMA on chunks 2ss, 2ss+1 (buffers written before last barrier)
        #pragma unroll
        for (int cc = 0; cc < 2; ++cc) {
            const _Float16* bb = s_inv + ((2 * ss + cc) & 3) * (64 * LDI) + l16 * LDI + quad * 8;
            #pragma unroll
            for (int nt = 0; nt < 4; ++nt) {
                const f16x8 bf = *(const f16x8*)(bb + nt * (16 * LDI));
                #pragma unroll
                for (int ct = 0; ct < 2; ++ct)
                    acc[ct][nt] = __builtin_amdgcn_mfma_f32_16x16x32_f16(Aa[pa][cc][ct], bf, acc[ct][nt], 0, 0, 0);
            }
        }
        __syncthreads();   // reads of 2ss,2ss+1 done; writes of 2ss+2,2ss+3 done
    }

    // ---- S[n] reduction over the 8 m-slice partials ----
    s_red[tid] = ssum;
    __syncthreads();
    if (tid < 64) {
        float t = 0.f;
        #pragma unroll
        for (int g = 0; g < 8; ++g) t += s_red[tid + 64 * g];
        s_recip[tid] = 1.0f / t;
    }
    __syncthreads();   // s_recip ready; xyz2/inv/red now dead -> s_X overlay safe

    // interp -> s_X[n][128 + c]
    {
        float rn4[4];
        #pragma unroll
        for (int nt = 0; nt < 4; ++nt) rn4[nt] = s_recip[nt * 16 + l16];
        #pragma unroll
        for (int ct = 0; ct < 2; ++ct)
            #pragma unroll
            for (int nt = 0; nt < 4; ++nt) {
                const f32x4 v = acc[ct][nt];
                const float r = rn4[nt];
                f16x4 hv;
                hv[0] = (_Float16)(v[0] * r);
                hv[1] = (_Float16)(v[1] * r);
                hv[2] = (_Float16)(v[2] * r);
                hv[3] = (_Float16)(v[3] * r);
                *(f16x4*)(&s_X[(nt * 16 + l16) * LDXc + 128 + w * 32 + ct * 16 + quad * 4]) = hv;
            }
    }
    // p1 -> s_X[n][c], c in [0,128): 8 c-groups of 16 over 8 waves
    {
        const float* p1b = p1 + (size_t)b * C1c * NPTS + n0;
        const int c0 = w * 16;
        #pragma unroll
        for (int cc = 0; cc < 4; ++cc) {
            const int c = c0 + cc * 4;
            f16x4 v;
            v[0] = (_Float16)p1b[(size_t)(c + 0) * NPTS + L];
            v[1] = (_Float16)p1b[(size_t)(c + 1) * NPTS + L];
            v[2] = (_Float16)p1b[(size_t)(c + 2) * NPTS + L];
            v[3] = (_Float16)p1b[(size_t)(c + 3) * NPTS + L];
            *(f16x4*)(&s_X[L * LDXc + c]) = v;
        }
    }
    __syncthreads();   // x matrix complete

    // ---------------- Phase B: h = relu(W1 @ x + b1), K=384 ----------------
    f32x4 hacc[2][4];
    #pragma unroll
    for (int ct = 0; ct < 2; ++ct)
        #pragma unroll
        for (int nt = 0; nt < 4; ++nt)
            hacc[ct][nt] = (f32x4){0.f, 0.f, 0.f, 0.f};

    #pragma unroll 2
    for (int kc = 0; kc < 12; ++kc) {
        f16x8 af[2];
        if (F16P) {
            const _Float16* wp = W1h + (size_t)(w * 32 + l16) * CINc + kc * 32 + quad * 8;
            #pragma unroll
            for (int ct = 0; ct < 2; ++ct) af[ct] = *(const f16x8*)(wp + ct * (16 * CINc));
        } else {
            const float* wp = W1 + (size_t)(w * 32 + l16) * CINc + kc * 32 + quad * 8;
            #pragma unroll
            for (int ct = 0; ct < 2; ++ct) {
                const float4 a0 = *(const float4*)(wp + ct * (16 * CINc));
                const float4 a1 = *(const float4*)(wp + ct * (16 * CINc) + 4);
                f16x8 h;
                h[0] = (_Float16)a0.x; h[1] = (_Float16)a0.y; h[2] = (_Float16)a0.z; h[3] = (_Float16)a0.w;
                h[4] = (_Float16)a1.x; h[5] = (_Float16)a1.y; h[6] = (_Float16)a1.z; h[7] = (_Float16)a1.w;
                af[ct] = h;
            }
        }
        #pragma unroll
        for (int nt = 0; nt < 4; ++nt) {
            const f16x8 bf = *(const f16x8*)(&s_X[(nt * 16 + l16) * LDXc + kc * 32 + quad * 8]);
            #pragma unroll
            for (int ct = 0; ct < 2; ++ct)
                hacc[ct][nt] = __builtin_amdgcn_mfma_f32_16x16x32_f16(af[ct], bf, hacc[ct][nt], 0, 0, 0);
        }
    }

    __syncthreads();   // all s_X reads done before overlaying s_H

    // bias + relu + stage h -> s_H[n][o1]  (wave w owns o1 rows [w*32, w*32+32))
    {
        f32x4 bb[2];
        #pragma unroll
        for (int ct = 0; ct < 2; ++ct)
            bb[ct] = *(const f32x4*)(b1v + w * 32 + ct * 16 + quad * 4);
        #pragma unroll
        for (int ct = 0; ct < 2; ++ct)
            #pragma unroll
            for (int nt = 0; nt < 4; ++nt) {
                const f32x4 v = hacc[ct][nt];
                f16x4 hv;
                hv[0] = (_Float16)fmaxf(v[0] + bb[ct][0], 0.f);
                hv[1] = (_Float16)fmaxf(v[1] + bb[ct][1], 0.f);
                hv[2] = (_Float16)fmaxf(v[2] + bb[ct][2], 0.f);
                hv[3] = (_Float16)fmaxf(v[3] + bb[ct][3], 0.f);
                *(f16x4*)(&s_H[(nt * 16 + l16) * LDH + w * 32 + ct * 16 + quad * 4]) = hv;
            }
    }
    __syncthreads();

    // ---------------- Phase C: out = relu(W2 @ h + b2), K=256 ----------------
    // wave w owns o2 rows [w*16, w*16+16)
    f32x4 oacc[4];
    #pragma unroll
    for (int nt = 0; nt < 4; ++nt)
        oacc[nt] = (f32x4){0.f, 0.f, 0.f, 0.f};

    #pragma unroll 2
    for (int oc = 0; oc < 8; ++oc) {
        f16x8 af2;
        if (F16P) {
            af2 = *(const f16x8*)(W2h + (size_t)(w * 16 + l16) * H1c + oc * 32 + quad * 8);
        } else {
            const float* wp = W2 + (size_t)(w * 16 + l16) * H1c + oc * 32 + quad * 8;
            const float4 a0 = *(const float4*)(wp);
            const float4 a1 = *(const float4*)(wp + 4);
            f16x8 h;
            h[0] = (_Float16)a0.x; h[1] = (_Float16)a0.y; h[2] = (_Float16)a0.z; h[3] = (_Float16)a0.w;
            h[4] = (_Float16)a1.x; h[5] = (_Float16)a1.y; h[6] = (_Float16)a1.z; h[7] = (_Float16)a1.w;
            af2 = h;
        }
        #pragma unroll
        for (int nt = 0; nt < 4; ++nt) {
            const f16x8 bf = *(const f16x8*)(&s_H[(nt * 16 + l16) * LDH + oc * 32 + quad * 8]);
            oacc[nt] = __builtin_amdgcn_mfma_f32_16x16x32_f16(af2, bf, oacc[nt], 0, 0, 0);
        }
    }

    // epilogue: bias + relu + store (rows w*16 + quad*4 + j)
    {
        const f32x4 bb2 = *(const f32x4*)(b2v + w * 16 + quad * 4);
        #pragma unroll
        for (int nt = 0; nt < 4; ++nt) {
            float* op = out + ((size_t)b * H2c + w * 16 + quad * 4) * NPTS
                            + n0 + nt * 16 + l16;
            #pragma unroll
            for (int j = 0; j < 4; ++j)
                op[(size_t)j * NPTS] = fmaxf(oacc[nt][j] + bb2[j], 0.f);
        }
    }
}

extern "C" void kernel_launch(void* const* d_in, const int* in_sizes, int n_in,
                              void* d_out, int out_size, void* d_ws, size_t ws_size,
                              hipStream_t stream) {
    (void)in_sizes; (void)n_in; (void)out_size;
    const float* xyz1 = (const float*)d_in[0];
    const float* xyz2 = (const float*)d_in[1];
    const float* p1   = (const float*)d_in[2];
    const float* p2   = (const float*)d_in[3];
    const float* W1   = (const float*)d_in[4];
    const float* b1   = (const float*)d_in[5];
    const float* W2   = (const float*)d_in[6];
    const float* b2   = (const float*)d_in[7];
    float* out = (float*)d_out;

    const bool useh = (ws_size >= (size_t)WS_F16_TOTAL * 2);
    dim3 grid(BBATCH * (NPTS / TN));   // 1024 blocks
    dim3 block(512);
    if (useh) {
        _Float16* ws = (_Float16*)d_ws;
        const int ncvt = (BBATCH * C2c * MPTS + H1c * CINc + H2c * H1c) / 4;  // 1081344
        cvt_f16<<<dim3(ncvt / 256), dim3(256), 0, stream>>>(p2, W1, W2, ws);
        fp_mfma4<true><<<grid, block, 0, stream>>>(xyz1, xyz2, p1, p2, W1, b1, W2, b2,
                                                   ws + WS_P2H, ws + WS_W1H, ws + WS_W2H, out);
    } else {
        fp_mfma4<false><<<grid, block, 0, stream>>>(xyz1, xyz2, p1, p2, W1, b1, W2, b2,
                                                    nullptr, nullptr, nullptr, out);
    }
}